// Round 21
// baseline (89.349 us; speedup 1.0000x reference)
//
#include <hip/hip_runtime.h>
#include <math.h>

#define Nn 512
#define Tt 8
#define Ee 16384
#define NNc (Nn*Nn)          // 262144
#define TNr (Tt*Nn)          // 4096
#define TE  (Tt*Ee)          // 131072
#define CAP 128              // bucket capacity per (t,dst); Poisson(32) => overflow ~1e-35

typedef __bf16 bf16x8 __attribute__((ext_vector_type(8)));
typedef float  f32x4  __attribute__((ext_vector_type(4)));
union BU { uint4 q; bf16x8 v; };

// RNE fp32 -> bf16 hi/lo split, packing two elements into one u32 each.
__device__ __forceinline__ void dec2(float x0, float x1, unsigned &hi, unsigned &lo){
    unsigned u0 = __float_as_uint(x0), u1 = __float_as_uint(x1);
    unsigned t0 = u0 + 0x7FFFu + ((u0>>16)&1u);
    unsigned t1 = u1 + 0x7FFFu + ((u1>>16)&1u);
    hi = (t0>>16) | (t1 & 0xFFFF0000u);
    float h0 = __uint_as_float(t0 & 0xFFFF0000u);
    float h1 = __uint_as_float(t1 & 0xFFFF0000u);
    float l0 = x0 - h0, l1 = x1 - h1;
    unsigned v0 = __float_as_uint(l0), v1 = __float_as_uint(l1);
    unsigned s0 = v0 + 0x7FFFu + ((v0>>16)&1u);
    unsigned s1 = v1 + 0x7FFFu + ((v1>>16)&1u);
    lo = (s0>>16) | (s1 & 0xFFFF0000u);
}

__device__ __forceinline__ void splitw(float x, unsigned short* ph, unsigned short* pl, int idx){
    unsigned u = __float_as_uint(x);
    unsigned t = u + 0x7FFFu + ((u>>16)&1u);
    ph[idx] = (unsigned short)(t>>16);
    float hf = __uint_as_float(t & 0xFFFF0000u);
    float lf = x - hf;
    unsigned v = __float_as_uint(lf);
    unsigned s = v + 0x7FFFu + ((v>>16)&1u);
    pl[idx] = (unsigned short)(s>>16);
}

// builds A hi/lo fragments from 8 consecutive fp32 (2 float4s)
#define DECA(Ah, Al, xa, ya) { uint4 hq, lq; \
    dec2(xa.x, xa.y, hq.x, lq.x); \
    dec2(xa.z, xa.w, hq.y, lq.y); \
    dec2(ya.x, ya.y, hq.z, lq.z); \
    dec2(ya.z, ya.w, hq.w, lq.w); \
    Ah.q = hq; Al.q = lq; }

// ---------------- prep: targeted zero (tag/cnt/out) + bf16 hi/lo splits of
// W3, Wp1, Wp2, W1(zero-padded K 80->96), W2 — all in MFMA B-fragment order.
__global__ __launch_bounds__(256) void k_prep(
    const int* __restrict__ ei, const float* __restrict__ W3,
    const float* __restrict__ Wp1, const float* __restrict__ Wp2,
    const float* __restrict__ W1, const float* __restrict__ W2,
    unsigned short* __restrict__ w3h, unsigned short* __restrict__ w3l,
    unsigned short* __restrict__ p1h, unsigned short* __restrict__ p1l,
    unsigned short* __restrict__ p2h, unsigned short* __restrict__ p2l,
    unsigned short* __restrict__ p3h, unsigned short* __restrict__ p3l,
    unsigned short* __restrict__ w2h, unsigned short* __restrict__ w2l,
    int* __restrict__ cnt, int* __restrict__ tag, float4* __restrict__ out4)
{
    int tid = threadIdx.x;
    int bid = blockIdx.x;
    if (bid < 64){
        int e = bid*256 + tid;   // < 16384
        int a = ei[7*2*Ee + e], b = ei[7*2*Ee + Ee + e];
        int cell = a*Nn + b;
#pragma unroll
        for (int t=0;t<8;++t) tag[t*NNc + cell] = 0;
        if (e < TNr) cnt[e] = 0;
        float4 z = {0.f,0.f,0.f,0.f};
#pragma unroll
        for (int q=0;q<4;++q) out4[q*16384 + e] = z;
        // W3 split: [128][128], 8 jt x 4 kt
        int i    = e & 7;
        int lane = (e>>3) & 63;
        int jt   = (e>>9) & 7;
        int kt   = e>>12;
        splitw(W3[(kt*32+(lane>>4)*8+i)*128 + jt*16+(lane&15)], w3h, w3l, e);
        return;
    }
    if (bid < 192){   // Wp1 [128][256]: 16 jt x 4 kt = 32768 elems
        int idx = (bid-64)*256 + tid;
        int i=idx&7, lane=(idx>>3)&63, jt=(idx>>9)&15, kt=idx>>13;
        splitw(Wp1[(kt*32+(lane>>4)*8+i)*256 + jt*16+(lane&15)], p1h, p1l, idx);
        return;
    }
    if (bid < 256){   // Wp2 [256][64]: 4 jt x 8 kt = 16384 elems
        int idx = (bid-192)*256 + tid;
        int i=idx&7, lane=(idx>>3)&63, jt=(idx>>9)&3, kt=idx>>11;
        splitw(Wp2[(kt*32+(lane>>4)*8+i)*64 + jt*16+(lane&15)], p2h, p2l, idx);
        return;
    }
    if (bid < 304){   // W1 [80][128] padded to K=96: 8 jt x 3 kt = 12288 elems
        int idx = (bid-256)*256 + tid;
        int i=idx&7, lane=(idx>>3)&63, jt=(idx>>9)&7, kt=idx>>12;
        int k = kt*32+(lane>>4)*8+i;
        float v = (k < 80) ? W1[k*128 + jt*16+(lane&15)] : 0.f;
        splitw(v, p3h, p3l, idx);
        return;
    }
    {                 // W2 [128][128]: 8 jt x 4 kt = 16384 elems
        int idx = (bid-304)*256 + tid;
        int i=idx&7, lane=(idx>>3)&63, jt=(idx>>9)&7, kt=idx>>12;
        splitw(W2[(kt*32+(lane>>4)*8+i)*128 + jt*16+(lane&15)], w2h, w2l, idx);
    }
}

// ---------------- k_mid: blocks 0..127 = fp3 (all 3 feat_proj/WLE1 layers via
// split-bf16 MFMA, 32 rows/block, h1+emb in LDS); blocks 128..639 = histtag.
__global__ __launch_bounds__(256) void k_mid(
    const int* __restrict__ ei, const float* __restrict__ ew,
    int* __restrict__ cnt, int2* __restrict__ bucket2, int* __restrict__ tag,
    const float* __restrict__ feats, const float* __restrict__ noise,
    const uint4* __restrict__ p1h, const uint4* __restrict__ p1l,
    const float* __restrict__ bp1,
    const uint4* __restrict__ p2h, const uint4* __restrict__ p2l,
    const float* __restrict__ bp2,
    const uint4* __restrict__ p3h, const uint4* __restrict__ p3l,
    const float* __restrict__ b1, float* __restrict__ hh)
{
    __shared__ float h1s[32][260];   // 33.3 KB
    __shared__ float embs[32][100];  // 12.8 KB
    int tid = threadIdx.x;
    if (blockIdx.x >= 128){
        // ---- histtag
        int g = (blockIdx.x - 128)*256 + tid;       // < T*E
        int t = g>>14, e = g&(Ee-1);
        int a = ei[t*2*Ee + e];
        int b = ei[t*2*Ee + Ee + e];
        int cell = t*Nn + a;
        int pos = atomicAdd(&cnt[cell], 1);
        if (pos < CAP) bucket2[(size_t)cell*CAP + pos] = make_int2(b, __float_as_int(ew[g]));
        atomicMax(&tag[t*NNc + a*Nn + b], g+1);
        return;
    }
    // ---- fp3
    int w = tid >> 6, lane = tid & 63;
    int r16 = lane & 15, g4 = lane >> 4;
    int r0 = blockIdx.x*32;
    {
        int row = tid >> 3, c2 = (tid & 7)*2;
        float2 nz = *(const float2*)&noise[(size_t)(r0+row)*16 + c2];
        embs[row][64+c2] = nz.x; embs[row][64+c2+1] = nz.y;
        embs[row][80+c2] = 0.f;  embs[row][80+c2+1] = 0.f;
    }
    // ======== L1
    const float* __restrict__ pa0 = &feats[(size_t)(r0 + r16)*128];
    const float* __restrict__ pa1 = &feats[(size_t)(r0 + 16 + r16)*128];
    {
        f32x4 a1[4][2];
#pragma unroll
        for (int jl=0;jl<4;++jl){ a1[jl][0]=(f32x4){0,0,0,0}; a1[jl][1]=(f32x4){0,0,0,0}; }
#pragma unroll
        for (int kt=0;kt<4;++kt){
            int k0 = kt*32 + g4*8;
            BU Ah0, Al0, Ah1, Al1;
            { float4 xa=*(const float4*)&pa0[k0], ya=*(const float4*)&pa0[k0+4]; DECA(Ah0,Al0,xa,ya) }
            { float4 xa=*(const float4*)&pa1[k0], ya=*(const float4*)&pa1[k0+4]; DECA(Ah1,Al1,xa,ya) }
#pragma unroll
            for (int jl=0;jl<4;++jl){
                int jt = w*4 + jl;
                BU Bh, Bl;
                Bh.q = p1h[(kt*16+jt)*64 + lane];
                Bl.q = p1l[(kt*16+jt)*64 + lane];
                a1[jl][0] = __builtin_amdgcn_mfma_f32_16x16x32_bf16(Ah0.v, Bh.v, a1[jl][0], 0,0,0);
                a1[jl][0] = __builtin_amdgcn_mfma_f32_16x16x32_bf16(Ah0.v, Bl.v, a1[jl][0], 0,0,0);
                a1[jl][0] = __builtin_amdgcn_mfma_f32_16x16x32_bf16(Al0.v, Bh.v, a1[jl][0], 0,0,0);
                a1[jl][1] = __builtin_amdgcn_mfma_f32_16x16x32_bf16(Ah1.v, Bh.v, a1[jl][1], 0,0,0);
                a1[jl][1] = __builtin_amdgcn_mfma_f32_16x16x32_bf16(Ah1.v, Bl.v, a1[jl][1], 0,0,0);
                a1[jl][1] = __builtin_amdgcn_mfma_f32_16x16x32_bf16(Al1.v, Bh.v, a1[jl][1], 0,0,0);
            }
        }
#pragma unroll
        for (int jl=0;jl<4;++jl){
            int jcol = (w*4+jl)*16 + r16;
            float b = bp1[jcol];
#pragma unroll
            for (int r=0;r<4;++r){
                h1s[g4*4+r][jcol]      = fmaxf(a1[jl][0][r] + b, 0.f);
                h1s[16+g4*4+r][jcol]   = fmaxf(a1[jl][1][r] + b, 0.f);
            }
        }
    }
    __syncthreads();
    // ======== L2
    {
        f32x4 a2[2];
        a2[0]=(f32x4){0,0,0,0}; a2[1]=(f32x4){0,0,0,0};
#pragma unroll
        for (int kt=0;kt<8;++kt){
            int k0 = kt*32 + g4*8;
            BU Ah0, Al0, Ah1, Al1;
            { float4 xa=*(const float4*)&h1s[r16][k0],    ya=*(const float4*)&h1s[r16][k0+4];    DECA(Ah0,Al0,xa,ya) }
            { float4 xa=*(const float4*)&h1s[16+r16][k0], ya=*(const float4*)&h1s[16+r16][k0+4]; DECA(Ah1,Al1,xa,ya) }
            BU Bh, Bl;
            Bh.q = p2h[(kt*4+w)*64 + lane];
            Bl.q = p2l[(kt*4+w)*64 + lane];
            a2[0] = __builtin_amdgcn_mfma_f32_16x16x32_bf16(Ah0.v, Bh.v, a2[0], 0,0,0);
            a2[0] = __builtin_amdgcn_mfma_f32_16x16x32_bf16(Ah0.v, Bl.v, a2[0], 0,0,0);
            a2[0] = __builtin_amdgcn_mfma_f32_16x16x32_bf16(Al0.v, Bh.v, a2[0], 0,0,0);
            a2[1] = __builtin_amdgcn_mfma_f32_16x16x32_bf16(Ah1.v, Bh.v, a2[1], 0,0,0);
            a2[1] = __builtin_amdgcn_mfma_f32_16x16x32_bf16(Ah1.v, Bl.v, a2[1], 0,0,0);
            a2[1] = __builtin_amdgcn_mfma_f32_16x16x32_bf16(Al1.v, Bh.v, a2[1], 0,0,0);
        }
        int jcol = w*16 + r16;
        float b = bp2[jcol];
#pragma unroll
        for (int r=0;r<4;++r){
            embs[g4*4+r][jcol]    = fmaxf(a2[0][r] + b, 0.f);
            embs[16+g4*4+r][jcol] = fmaxf(a2[1][r] + b, 0.f);
        }
    }
    __syncthreads();
    // ======== L3
    {
        f32x4 a3[2][2];
#pragma unroll
        for (int jl=0;jl<2;++jl){ a3[jl][0]=(f32x4){0,0,0,0}; a3[jl][1]=(f32x4){0,0,0,0}; }
#pragma unroll
        for (int kt=0;kt<3;++kt){
            int k0 = kt*32 + g4*8;
            BU Ah0, Al0, Ah1, Al1;
            { float4 xa=*(const float4*)&embs[r16][k0],    ya=*(const float4*)&embs[r16][k0+4];    DECA(Ah0,Al0,xa,ya) }
            { float4 xa=*(const float4*)&embs[16+r16][k0], ya=*(const float4*)&embs[16+r16][k0+4]; DECA(Ah1,Al1,xa,ya) }
#pragma unroll
            for (int jl=0;jl<2;++jl){
                int jt = w*2 + jl;
                BU Bh, Bl;
                Bh.q = p3h[(kt*8+jt)*64 + lane];
                Bl.q = p3l[(kt*8+jt)*64 + lane];
                a3[jl][0] = __builtin_amdgcn_mfma_f32_16x16x32_bf16(Ah0.v, Bh.v, a3[jl][0], 0,0,0);
                a3[jl][0] = __builtin_amdgcn_mfma_f32_16x16x32_bf16(Ah0.v, Bl.v, a3[jl][0], 0,0,0);
                a3[jl][0] = __builtin_amdgcn_mfma_f32_16x16x32_bf16(Al0.v, Bh.v, a3[jl][0], 0,0,0);
                a3[jl][1] = __builtin_amdgcn_mfma_f32_16x16x32_bf16(Ah1.v, Bh.v, a3[jl][1], 0,0,0);
                a3[jl][1] = __builtin_amdgcn_mfma_f32_16x16x32_bf16(Ah1.v, Bl.v, a3[jl][1], 0,0,0);
                a3[jl][1] = __builtin_amdgcn_mfma_f32_16x16x32_bf16(Al1.v, Bh.v, a3[jl][1], 0,0,0);
            }
        }
#pragma unroll
        for (int jl=0;jl<2;++jl){
            int jcol = (w*2+jl)*16 + r16;
            float b = b1[jcol];
#pragma unroll
            for (int r=0;r<4;++r){
                hh[(size_t)(r0+g4*4+r)*128 + jcol]    = fmaxf(a3[jl][0][r] + b, 0.f);
                hh[(size_t)(r0+16+g4*4+r)*128 + jcol] = fmaxf(a3[jl][1][r] + b, 0.f);
            }
        }
    }
}

// ---------------- k_sw2: 16 dsts/block; gather x rows into LDS (same pairwise
// sum order as before), then h2 = relu(x @ W2) via split-bf16 MFMA.
__global__ __launch_bounds__(512) void k_sw2(
    const float* __restrict__ hh, const int* __restrict__ cnt,
    const int2* __restrict__ bucket2,
    const uint4* __restrict__ w2h, const uint4* __restrict__ w2l,
    const float* __restrict__ b2, float* __restrict__ h2)
{
    __shared__ float sx[16][132];
    int tid = threadIdx.x;
    int bidd0 = blockIdx.x * 16;
    {
        int dloc = tid >> 5;          // 0..15
        int j4 = tid & 31;            // float4 column group
        int cell = bidd0 + dloc;
        int t = cell >> 9;
        int n = cnt[cell]; n = n < CAP ? n : CAP;
        const int2* __restrict__ bk = &bucket2[(size_t)cell*CAP];
        const float* __restrict__ hht = &hh[(size_t)t*Nn*128];
        float4 acc = *(const float4*)&hh[(size_t)cell*128 + j4*4];
        int i = 0;
        for (; i+1 < n; i += 2){
            int2 p0 = bk[i], p1 = bk[i+1];
            float w0 = __int_as_float(p0.y), w1 = __int_as_float(p1.y);
            float4 r0 = *(const float4*)&hht[(size_t)p0.x*128 + j4*4];
            float4 r1 = *(const float4*)&hht[(size_t)p1.x*128 + j4*4];
            acc.x += w0*r0.x + w1*r1.x;
            acc.y += w0*r0.y + w1*r1.y;
            acc.z += w0*r0.z + w1*r1.z;
            acc.w += w0*r0.w + w1*r1.w;
        }
        if (i < n){
            int2 p = bk[i];
            float w = __int_as_float(p.y);
            float4 r = *(const float4*)&hht[(size_t)p.x*128 + j4*4];
            acc.x += w*r.x; acc.y += w*r.y; acc.z += w*r.z; acc.w += w*r.w;
        }
        *(float4*)&sx[dloc][j4*4] = acc;
    }
    __syncthreads();
    // MFMA: h2[16 x 128] = relu(sx @ W2 + b2); wave w owns jt = w (8 waves)
    int w = tid >> 6, lane = tid & 63;
    int r16 = lane & 15, g4 = lane >> 4;
    f32x4 a = (f32x4){0.f,0.f,0.f,0.f};
#pragma unroll
    for (int kt=0;kt<4;++kt){
        int k0 = kt*32 + g4*8;
        BU Ah, Al;
        { float4 xa = *(const float4*)&sx[r16][k0]; float4 ya = *(const float4*)&sx[r16][k0+4]; DECA(Ah,Al,xa,ya) }
        BU Bh, Bl;
        Bh.q = w2h[(kt*8+w)*64 + lane];
        Bl.q = w2l[(kt*8+w)*64 + lane];
        a = __builtin_amdgcn_mfma_f32_16x16x32_bf16(Ah.v, Bh.v, a, 0,0,0);
        a = __builtin_amdgcn_mfma_f32_16x16x32_bf16(Ah.v, Bl.v, a, 0,0,0);
        a = __builtin_amdgcn_mfma_f32_16x16x32_bf16(Al.v, Bh.v, a, 0,0,0);
    }
    int jcol = w*16 + r16;
    float b = b2[jcol];
#pragma unroll
    for (int r=0;r<4;++r)
        h2[(size_t)(bidd0 + g4*4 + r)*128 + jcol] = fmaxf(a[r] + b, 0.f);
}

// ---------------- edge scores via split-bf16 MFMA, fragment-pipelined.
// 256 threads (4 waves), 128 edges/block, grid 1024: LDS 64 KB x 2 blocks/CU
// fits 128/160 KB; staging of block B overlaps MFMA of block A.
__global__ __launch_bounds__(256) void k_edge9(
    const int* __restrict__ ei, const float* __restrict__ h2,
    const uint4* __restrict__ w3h, const uint4* __restrict__ w3l,
    const float* __restrict__ b3, const float* __restrict__ w4,
    const float* __restrict__ b4, float* __restrict__ sc)
{
    __shared__ uint4 sBh[2048];   // 32 KB
    __shared__ uint4 sBl[2048];   // 32 KB
    int tid = threadIdx.x;
    int bid = blockIdx.x;                  // < 1024
#pragma unroll
    for (int q=0;q<8;++q){
        sBh[q*256+tid] = w3h[q*256+tid];
        sBl[q*256+tid] = w3l[q*256+tid];
    }
    int tb  = bid >> 7;                    // timestep (128 blocks/t)
    int e0b = (bid & 127) * 128;
    int w   = tid >> 6, lane = tid & 63;
    int e0w = e0b + w*32;
    int r16 = lane & 15, g4 = lane >> 4;

    const int* __restrict__ eit = &ei[tb*2*Ee];
    int a0 = eit[e0w + r16],      s0 = eit[Ee + e0w + r16];
    int a1 = eit[e0w + 16 + r16], s1 = eit[Ee + e0w + 16 + r16];
    const float* __restrict__ pa0 = &h2[(size_t)(tb*Nn+a0)*128];
    const float* __restrict__ pb0 = &h2[(size_t)(tb*Nn+s0)*128];
    const float* __restrict__ pa1 = &h2[(size_t)(tb*Nn+a1)*128];
    const float* __restrict__ pb1 = &h2[(size_t)(tb*Nn+s1)*128];

    f32x4 acc0[8], acc1[8];
#pragma unroll
    for (int jt=0;jt<8;++jt){
        acc0[jt] = (f32x4){0.f,0.f,0.f,0.f};
        acc1[jt] = (f32x4){0.f,0.f,0.f,0.f};
    }

    float4 rA0,rA1,rB0,rB1,rC0,rC1,rD0,rD1;
#define LOADK(kt) { int k0=(kt)*32+g4*8; \
    rA0=*(const float4*)&pa0[k0]; rA1=*(const float4*)&pa0[k0+4]; \
    rB0=*(const float4*)&pb0[k0]; rB1=*(const float4*)&pb0[k0+4]; \
    rC0=*(const float4*)&pa1[k0]; rC1=*(const float4*)&pa1[k0+4]; \
    rD0=*(const float4*)&pb1[k0]; rD1=*(const float4*)&pb1[k0+4]; }

    BU ah0[2], al0[2], ah1[2], al1[2];
#define DECK(s) { uint4 hq,lq; \
    dec2(rA0.x*rB0.x, rA0.y*rB0.y, hq.x, lq.x); \
    dec2(rA0.z*rB0.z, rA0.w*rB0.w, hq.y, lq.y); \
    dec2(rA1.x*rB1.x, rA1.y*rB1.y, hq.z, lq.z); \
    dec2(rA1.z*rB1.z, rA1.w*rB1.w, hq.w, lq.w); \
    ah0[s].q=hq; al0[s].q=lq; \
    dec2(rC0.x*rD0.x, rC0.y*rD0.y, hq.x, lq.x); \
    dec2(rC0.z*rD0.z, rC0.w*rD0.w, hq.y, lq.y); \
    dec2(rC1.x*rD1.x, rC1.y*rD1.y, hq.z, lq.z); \
    dec2(rC1.z*rD1.z, rC1.w*rD1.w, hq.w, lq.w); \
    ah1[s].q=hq; al1[s].q=lq; }

    LOADK(0)
    DECK(0)
    __syncthreads();
#pragma unroll
    for (int kt=0;kt<4;++kt){
        if (kt < 3) LOADK(kt+1)
        const int s = kt & 1;
#pragma unroll
        for (int jt=0;jt<8;++jt){
            BU Bh, Bl;
            Bh.q = sBh[(kt*8+jt)*64 + lane];
            Bl.q = sBl[(kt*8+jt)*64 + lane];
            acc0[jt] = __builtin_amdgcn_mfma_f32_16x16x32_bf16(ah0[s].v, Bh.v, acc0[jt], 0,0,0);
            acc0[jt] = __builtin_amdgcn_mfma_f32_16x16x32_bf16(ah0[s].v, Bl.v, acc0[jt], 0,0,0);
            acc0[jt] = __builtin_amdgcn_mfma_f32_16x16x32_bf16(al0[s].v, Bh.v, acc0[jt], 0,0,0);
            acc1[jt] = __builtin_amdgcn_mfma_f32_16x16x32_bf16(ah1[s].v, Bh.v, acc1[jt], 0,0,0);
            acc1[jt] = __builtin_amdgcn_mfma_f32_16x16x32_bf16(ah1[s].v, Bl.v, acc1[jt], 0,0,0);
            acc1[jt] = __builtin_amdgcn_mfma_f32_16x16x32_bf16(al1[s].v, Bh.v, acc1[jt], 0,0,0);
        }
        if (kt < 3) DECK((kt+1)&1)
    }

    float b4v = b4[0];
    float b3v[8], w4v[8];
#pragma unroll
    for (int jt=0;jt<8;++jt){ b3v[jt] = b3[jt*16 + r16]; w4v[jt] = w4[jt*16 + r16]; }
#pragma unroll
    for (int r=0;r<4;++r){
        float p0 = 0.f, p1 = 0.f;
#pragma unroll
        for (int jt=0;jt<8;++jt){
            p0 += fmaxf(acc0[jt][r] + b3v[jt], 0.f) * w4v[jt];
            p1 += fmaxf(acc1[jt][r] + b3v[jt], 0.f) * w4v[jt];
        }
        p0 += __shfl_xor(p0,1); p0 += __shfl_xor(p0,2);
        p0 += __shfl_xor(p0,4); p0 += __shfl_xor(p0,8);
        p1 += __shfl_xor(p1,1); p1 += __shfl_xor(p1,2);
        p1 += __shfl_xor(p1,4); p1 += __shfl_xor(p1,8);
        if (r16 == 0){
            sc[(size_t)tb*Ee + e0w + g4*4 + r]      = p0 + b4v;
            sc[(size_t)tb*Ee + e0w + 16 + g4*4 + r] = p1 + b4v;
        }
    }
}

// ---------------- SSM recurrence (reads tag+sc directly)
__global__ __launch_bounds__(256) void k_ssm2(
    const int* __restrict__ ei, const int* __restrict__ tag,
    const float* __restrict__ sc,
    const float* __restrict__ W_in, const float* __restrict__ conv_w,
    const float* __restrict__ conv_b, const float* __restrict__ dt_bias,
    const float* __restrict__ A_log, const float* __restrict__ D_skip,
    const float* __restrict__ W_out, float* __restrict__ out)
{
    __shared__ float scw[132], scb[33], swin[35];
    int tid = threadIdx.x;
    if (tid < 132) scw[tid] = conv_w[tid];
    if (tid < 33)  scb[tid] = conv_b[tid];
    if (tid < 35)  swin[tid] = W_in[tid];
    __syncthreads();

    int e = blockIdx.x*256 + tid;              // < E
    int a = ei[7*2*Ee + e], b = ei[7*2*Ee + Ee + e];
    int cell = a*Nn + b;
    float x[8];
#pragma unroll
    for (int t=0;t<8;++t){
        int tg = tag[t*NNc + cell];
        x[t] = (tg > 0) ? sc[tg-1] : 0.f;
    }

    float A    = -expf(A_log[0]);
    float dtb  = dt_bias[0];
    float dsk  = D_skip[0];
    float wout = W_out[0];
    float win_z = swin[0], win_dt = swin[34];

    float ssm[16];
#pragma unroll
    for (int q=0;q<16;++q) ssm[q]=0.f;
    float h0=0.f,h1=0.f,h2v=0.f;
    float y=0.f;
    for (int t=0;t<8;++t){
        float xt = x[t];
        float act[33];
#pragma unroll
        for (int c=0;c<33;++c){
            float s = h0*scw[c*4+0] + h1*scw[c*4+1] + h2v*scw[c*4+2] + xt*scw[c*4+3];
            float pre = swin[1+c]*s + scb[c];
            act[c] = pre / (1.f + expf(-pre));
        }
        float x_ = act[0];
        float dtr = xt*win_dt + dtb;
        float dt  = (dtr > 20.f) ? dtr : log1pf(expf(dtr));
        float dA  = expf(dt*A);
        float dx  = dt*x_;
        float yv = 0.f;
#pragma unroll
        for (int q=0;q<16;++q){
            ssm[q] = ssm[q]*dA + dx*act[1+q];
            yv += ssm[q]*act[17+q];
        }
        yv += dsk*x_;
        float z = xt*win_z;
        yv *= z / (1.f + expf(-z));
        y = yv;
        h0=h1; h1=h2v; h2v=xt;
    }
    out[cell] = y*wout;
}

extern "C" void kernel_launch(void* const* d_in, const int* in_sizes, int n_in,
                              void* d_out, int out_size, void* d_ws, size_t ws_size,
                              hipStream_t stream)
{
    const int*   ei    = (const int*)d_in[0];
    const float* ew    = (const float*)d_in[1];
    const float* feats = (const float*)d_in[2];
    const float* noise = (const float*)d_in[3];
    const float* Wp1=(const float*)d_in[4];  const float* bp1=(const float*)d_in[5];
    const float* Wp2=(const float*)d_in[6];  const float* bp2=(const float*)d_in[7];
    const float* W1 =(const float*)d_in[8];  const float* b1 =(const float*)d_in[9];
    const float* W2 =(const float*)d_in[10]; const float* b2 =(const float*)d_in[11];
    const float* W3 =(const float*)d_in[12]; const float* b3 =(const float*)d_in[13];
    const float* w4 =(const float*)d_in[14]; const float* b4 =(const float*)d_in[15];
    const float* W_in  =(const float*)d_in[16]; const float* conv_w=(const float*)d_in[17];
    const float* conv_b=(const float*)d_in[18]; const float* dt_bias=(const float*)d_in[19];
    const float* A_log =(const float*)d_in[20]; const float* D_skip=(const float*)d_in[21];
    const float* W_out =(const float*)d_in[22];

    float* out = (float*)d_out;
    float* ws  = (float*)d_ws;
    float* hh    = ws;                      // T*N*128  = 524288
    float* h2    = hh    + 524288;          // 524288
    float* sc    = h2    + 524288;          // T*E      = 131072
    int*   cnt   = (int*)(sc + 131072);     // T*N      = 4096
    int*   tag   = cnt + TNr;               // T*N*N    = 2097152
    int2*  bucket2 = (int2*)(tag + 2097152);           // T*N*CAP int2 = 4MB
    unsigned short* w3h = (unsigned short*)(bucket2 + (size_t)TNr*CAP);  // 16384
    unsigned short* w3l = w3h + 16384;      // 16384
    unsigned short* p1h = w3l + 16384;      // 32768
    unsigned short* p1l = p1h + 32768;      // 32768
    unsigned short* p2h = p1l + 32768;      // 16384
    unsigned short* p2l = p2h + 16384;      // 16384
    unsigned short* p3h = p2l + 16384;      // 12288
    unsigned short* p3l = p3h + 12288;      // 12288
    unsigned short* w2h = p3l + 12288;      // 16384
    unsigned short* w2l = w2h + 16384;      // 16384

    k_prep <<<368, 256, 0, stream>>>(ei, W3, Wp1, Wp2, W1, W2,
                                     w3h, w3l, p1h, p1l, p2h, p2l, p3h, p3l,
                                     w2h, w2l, cnt, tag, (float4*)out);
    k_mid  <<<640, 256, 0, stream>>>(ei, ew, cnt, bucket2, tag, feats, noise,
                                     (const uint4*)p1h, (const uint4*)p1l, bp1,
                                     (const uint4*)p2h, (const uint4*)p2l, bp2,
                                     (const uint4*)p3h, (const uint4*)p3l, b1, hh);
    k_sw2  <<<TNr/16, 512, 0, stream>>>(hh, cnt, bucket2,
                                        (const uint4*)w2h, (const uint4*)w2l, b2, h2);
    k_edge9<<<1024, 256, 0, stream>>>(ei, h2, (const uint4*)w3h, (const uint4*)w3l,
                                      b3, w4, b4, sc);
    k_ssm2 <<<Ee/256, 256, 0, stream>>>(ei, tag, sc, W_in, conv_w, conv_b,
                                        dt_bias, A_log, D_skip, W_out, out);
}

// Round 23
// 89.033 us; speedup vs baseline: 1.0036x; 1.0036x over previous
//
#include <hip/hip_runtime.h>
#include <math.h>

#define Nn 512
#define Tt 8
#define Ee 16384
#define NNc (Nn*Nn)          // 262144
#define TNr (Tt*Nn)          // 4096
#define TE  (Tt*Ee)          // 131072
#define CAP 128              // bucket capacity per (t,dst); Poisson(32) => overflow ~1e-35

typedef __bf16 bf16x8 __attribute__((ext_vector_type(8)));
typedef float  f32x4  __attribute__((ext_vector_type(4)));
union BU { uint4 q; bf16x8 v; };

// RNE fp32 -> bf16 hi/lo split, packing two elements into one u32 each.
__device__ __forceinline__ void dec2(float x0, float x1, unsigned &hi, unsigned &lo){
    unsigned u0 = __float_as_uint(x0), u1 = __float_as_uint(x1);
    unsigned t0 = u0 + 0x7FFFu + ((u0>>16)&1u);
    unsigned t1 = u1 + 0x7FFFu + ((u1>>16)&1u);
    hi = (t0>>16) | (t1 & 0xFFFF0000u);
    float h0 = __uint_as_float(t0 & 0xFFFF0000u);
    float h1 = __uint_as_float(t1 & 0xFFFF0000u);
    float l0 = x0 - h0, l1 = x1 - h1;
    unsigned v0 = __float_as_uint(l0), v1 = __float_as_uint(l1);
    unsigned s0 = v0 + 0x7FFFu + ((v0>>16)&1u);
    unsigned s1 = v1 + 0x7FFFu + ((v1>>16)&1u);
    lo = (s0>>16) | (s1 & 0xFFFF0000u);
}

__device__ __forceinline__ void splitw(float x, unsigned short* ph, unsigned short* pl, int idx){
    unsigned u = __float_as_uint(x);
    unsigned t = u + 0x7FFFu + ((u>>16)&1u);
    ph[idx] = (unsigned short)(t>>16);
    float hf = __uint_as_float(t & 0xFFFF0000u);
    float lf = x - hf;
    unsigned v = __float_as_uint(lf);
    unsigned s = v + 0x7FFFu + ((v>>16)&1u);
    pl[idx] = (unsigned short)(s>>16);
}

// builds A hi/lo fragments from 8 consecutive fp32 (2 float4s)
#define DECA(Ah, Al, xa, ya) { uint4 hq, lq; \
    dec2(xa.x, xa.y, hq.x, lq.x); \
    dec2(xa.z, xa.w, hq.y, lq.y); \
    dec2(ya.x, ya.y, hq.z, lq.z); \
    dec2(ya.z, ya.w, hq.w, lq.w); \
    Ah.q = hq; Al.q = lq; }

// ---------------- prep: targeted zero (tag/cnt/out) + bf16 hi/lo splits of
// W3, Wp1, Wp2, W1(zero-padded K 80->96), W2 — all in MFMA B-fragment order.
__global__ __launch_bounds__(256) void k_prep(
    const int* __restrict__ ei, const float* __restrict__ W3,
    const float* __restrict__ Wp1, const float* __restrict__ Wp2,
    const float* __restrict__ W1, const float* __restrict__ W2,
    unsigned short* __restrict__ w3h, unsigned short* __restrict__ w3l,
    unsigned short* __restrict__ p1h, unsigned short* __restrict__ p1l,
    unsigned short* __restrict__ p2h, unsigned short* __restrict__ p2l,
    unsigned short* __restrict__ p3h, unsigned short* __restrict__ p3l,
    unsigned short* __restrict__ w2h, unsigned short* __restrict__ w2l,
    int* __restrict__ cnt, int* __restrict__ tag, float4* __restrict__ out4)
{
    int tid = threadIdx.x;
    int bid = blockIdx.x;
    if (bid < 64){
        int e = bid*256 + tid;   // < 16384
        int a = ei[7*2*Ee + e], b = ei[7*2*Ee + Ee + e];
        int cell = a*Nn + b;
#pragma unroll
        for (int t=0;t<8;++t) tag[t*NNc + cell] = 0;
        if (e < TNr) cnt[e] = 0;
        float4 z = {0.f,0.f,0.f,0.f};
#pragma unroll
        for (int q=0;q<4;++q) out4[q*16384 + e] = z;
        // W3 split: [128][128], 8 jt x 4 kt
        int i    = e & 7;
        int lane = (e>>3) & 63;
        int jt   = (e>>9) & 7;
        int kt   = e>>12;
        splitw(W3[(kt*32+(lane>>4)*8+i)*128 + jt*16+(lane&15)], w3h, w3l, e);
        return;
    }
    if (bid < 192){   // Wp1 [128][256]: 16 jt x 4 kt = 32768 elems
        int idx = (bid-64)*256 + tid;
        int i=idx&7, lane=(idx>>3)&63, jt=(idx>>9)&15, kt=idx>>13;
        splitw(Wp1[(kt*32+(lane>>4)*8+i)*256 + jt*16+(lane&15)], p1h, p1l, idx);
        return;
    }
    if (bid < 256){   // Wp2 [256][64]: 4 jt x 8 kt = 16384 elems
        int idx = (bid-192)*256 + tid;
        int i=idx&7, lane=(idx>>3)&63, jt=(idx>>9)&3, kt=idx>>11;
        splitw(Wp2[(kt*32+(lane>>4)*8+i)*64 + jt*16+(lane&15)], p2h, p2l, idx);
        return;
    }
    if (bid < 304){   // W1 [80][128] padded to K=96: 8 jt x 3 kt = 12288 elems
        int idx = (bid-256)*256 + tid;
        int i=idx&7, lane=(idx>>3)&63, jt=(idx>>9)&7, kt=idx>>12;
        int k = kt*32+(lane>>4)*8+i;
        float v = (k < 80) ? W1[k*128 + jt*16+(lane&15)] : 0.f;
        splitw(v, p3h, p3l, idx);
        return;
    }
    {                 // W2 [128][128]: 8 jt x 4 kt = 16384 elems
        int idx = (bid-304)*256 + tid;
        int i=idx&7, lane=(idx>>3)&63, jt=(idx>>9)&7, kt=idx>>12;
        splitw(W2[(kt*32+(lane>>4)*8+i)*128 + jt*16+(lane&15)], w2h, w2l, idx);
    }
}

// ---------------- k_mid: blocks 0..127 = fp3 (all 3 feat_proj/WLE1 layers via
// split-bf16 MFMA, 32 rows/block, h1+emb in LDS); blocks 128..639 = histtag.
__global__ __launch_bounds__(256) void k_mid(
    const int* __restrict__ ei, const float* __restrict__ ew,
    int* __restrict__ cnt, int2* __restrict__ bucket2, int* __restrict__ tag,
    const float* __restrict__ feats, const float* __restrict__ noise,
    const uint4* __restrict__ p1h, const uint4* __restrict__ p1l,
    const float* __restrict__ bp1,
    const uint4* __restrict__ p2h, const uint4* __restrict__ p2l,
    const float* __restrict__ bp2,
    const uint4* __restrict__ p3h, const uint4* __restrict__ p3l,
    const float* __restrict__ b1, float* __restrict__ hh)
{
    __shared__ float h1s[32][260];   // 33.3 KB
    __shared__ float embs[32][100];  // 12.8 KB
    int tid = threadIdx.x;
    if (blockIdx.x >= 128){
        // ---- histtag
        int g = (blockIdx.x - 128)*256 + tid;       // < T*E
        int t = g>>14, e = g&(Ee-1);
        int a = ei[t*2*Ee + e];
        int b = ei[t*2*Ee + Ee + e];
        int cell = t*Nn + a;
        int pos = atomicAdd(&cnt[cell], 1);
        if (pos < CAP) bucket2[(size_t)cell*CAP + pos] = make_int2(b, __float_as_int(ew[g]));
        atomicMax(&tag[t*NNc + a*Nn + b], g+1);
        return;
    }
    // ---- fp3
    int w = tid >> 6, lane = tid & 63;
    int r16 = lane & 15, g4 = lane >> 4;
    int r0 = blockIdx.x*32;
    {
        int row = tid >> 3, c2 = (tid & 7)*2;
        float2 nz = *(const float2*)&noise[(size_t)(r0+row)*16 + c2];
        embs[row][64+c2] = nz.x; embs[row][64+c2+1] = nz.y;
        embs[row][80+c2] = 0.f;  embs[row][80+c2+1] = 0.f;
    }
    // ======== L1
    const float* __restrict__ pa0 = &feats[(size_t)(r0 + r16)*128];
    const float* __restrict__ pa1 = &feats[(size_t)(r0 + 16 + r16)*128];
    {
        f32x4 a1[4][2];
#pragma unroll
        for (int jl=0;jl<4;++jl){ a1[jl][0]=(f32x4){0,0,0,0}; a1[jl][1]=(f32x4){0,0,0,0}; }
#pragma unroll
        for (int kt=0;kt<4;++kt){
            int k0 = kt*32 + g4*8;
            BU Ah0, Al0, Ah1, Al1;
            { float4 xa=*(const float4*)&pa0[k0], ya=*(const float4*)&pa0[k0+4]; DECA(Ah0,Al0,xa,ya) }
            { float4 xa=*(const float4*)&pa1[k0], ya=*(const float4*)&pa1[k0+4]; DECA(Ah1,Al1,xa,ya) }
#pragma unroll
            for (int jl=0;jl<4;++jl){
                int jt = w*4 + jl;
                BU Bh, Bl;
                Bh.q = p1h[(kt*16+jt)*64 + lane];
                Bl.q = p1l[(kt*16+jt)*64 + lane];
                a1[jl][0] = __builtin_amdgcn_mfma_f32_16x16x32_bf16(Ah0.v, Bh.v, a1[jl][0], 0,0,0);
                a1[jl][0] = __builtin_amdgcn_mfma_f32_16x16x32_bf16(Ah0.v, Bl.v, a1[jl][0], 0,0,0);
                a1[jl][0] = __builtin_amdgcn_mfma_f32_16x16x32_bf16(Al0.v, Bh.v, a1[jl][0], 0,0,0);
                a1[jl][1] = __builtin_amdgcn_mfma_f32_16x16x32_bf16(Ah1.v, Bh.v, a1[jl][1], 0,0,0);
                a1[jl][1] = __builtin_amdgcn_mfma_f32_16x16x32_bf16(Ah1.v, Bl.v, a1[jl][1], 0,0,0);
                a1[jl][1] = __builtin_amdgcn_mfma_f32_16x16x32_bf16(Al1.v, Bh.v, a1[jl][1], 0,0,0);
            }
        }
#pragma unroll
        for (int jl=0;jl<4;++jl){
            int jcol = (w*4+jl)*16 + r16;
            float b = bp1[jcol];
#pragma unroll
            for (int r=0;r<4;++r){
                h1s[g4*4+r][jcol]      = fmaxf(a1[jl][0][r] + b, 0.f);
                h1s[16+g4*4+r][jcol]   = fmaxf(a1[jl][1][r] + b, 0.f);
            }
        }
    }
    __syncthreads();
    // ======== L2
    {
        f32x4 a2[2];
        a2[0]=(f32x4){0,0,0,0}; a2[1]=(f32x4){0,0,0,0};
#pragma unroll
        for (int kt=0;kt<8;++kt){
            int k0 = kt*32 + g4*8;
            BU Ah0, Al0, Ah1, Al1;
            { float4 xa=*(const float4*)&h1s[r16][k0],    ya=*(const float4*)&h1s[r16][k0+4];    DECA(Ah0,Al0,xa,ya) }
            { float4 xa=*(const float4*)&h1s[16+r16][k0], ya=*(const float4*)&h1s[16+r16][k0+4]; DECA(Ah1,Al1,xa,ya) }
            BU Bh, Bl;
            Bh.q = p2h[(kt*4+w)*64 + lane];
            Bl.q = p2l[(kt*4+w)*64 + lane];
            a2[0] = __builtin_amdgcn_mfma_f32_16x16x32_bf16(Ah0.v, Bh.v, a2[0], 0,0,0);
            a2[0] = __builtin_amdgcn_mfma_f32_16x16x32_bf16(Ah0.v, Bl.v, a2[0], 0,0,0);
            a2[0] = __builtin_amdgcn_mfma_f32_16x16x32_bf16(Al0.v, Bh.v, a2[0], 0,0,0);
            a2[1] = __builtin_amdgcn_mfma_f32_16x16x32_bf16(Ah1.v, Bh.v, a2[1], 0,0,0);
            a2[1] = __builtin_amdgcn_mfma_f32_16x16x32_bf16(Ah1.v, Bl.v, a2[1], 0,0,0);
            a2[1] = __builtin_amdgcn_mfma_f32_16x16x32_bf16(Al1.v, Bh.v, a2[1], 0,0,0);
        }
        int jcol = w*16 + r16;
        float b = bp2[jcol];
#pragma unroll
        for (int r=0;r<4;++r){
            embs[g4*4+r][jcol]    = fmaxf(a2[0][r] + b, 0.f);
            embs[16+g4*4+r][jcol] = fmaxf(a2[1][r] + b, 0.f);
        }
    }
    __syncthreads();
    // ======== L3
    {
        f32x4 a3[2][2];
#pragma unroll
        for (int jl=0;jl<2;++jl){ a3[jl][0]=(f32x4){0,0,0,0}; a3[jl][1]=(f32x4){0,0,0,0}; }
#pragma unroll
        for (int kt=0;kt<3;++kt){
            int k0 = kt*32 + g4*8;
            BU Ah0, Al0, Ah1, Al1;
            { float4 xa=*(const float4*)&embs[r16][k0],    ya=*(const float4*)&embs[r16][k0+4];    DECA(Ah0,Al0,xa,ya) }
            { float4 xa=*(const float4*)&embs[16+r16][k0], ya=*(const float4*)&embs[16+r16][k0+4]; DECA(Ah1,Al1,xa,ya) }
#pragma unroll
            for (int jl=0;jl<2;++jl){
                int jt = w*2 + jl;
                BU Bh, Bl;
                Bh.q = p3h[(kt*8+jt)*64 + lane];
                Bl.q = p3l[(kt*8+jt)*64 + lane];
                a3[jl][0] = __builtin_amdgcn_mfma_f32_16x16x32_bf16(Ah0.v, Bh.v, a3[jl][0], 0,0,0);
                a3[jl][0] = __builtin_amdgcn_mfma_f32_16x16x32_bf16(Ah0.v, Bl.v, a3[jl][0], 0,0,0);
                a3[jl][0] = __builtin_amdgcn_mfma_f32_16x16x32_bf16(Al0.v, Bh.v, a3[jl][0], 0,0,0);
                a3[jl][1] = __builtin_amdgcn_mfma_f32_16x16x32_bf16(Ah1.v, Bh.v, a3[jl][1], 0,0,0);
                a3[jl][1] = __builtin_amdgcn_mfma_f32_16x16x32_bf16(Ah1.v, Bl.v, a3[jl][1], 0,0,0);
                a3[jl][1] = __builtin_amdgcn_mfma_f32_16x16x32_bf16(Al1.v, Bh.v, a3[jl][1], 0,0,0);
            }
        }
#pragma unroll
        for (int jl=0;jl<2;++jl){
            int jcol = (w*2+jl)*16 + r16;
            float b = b1[jcol];
#pragma unroll
            for (int r=0;r<4;++r){
                hh[(size_t)(r0+g4*4+r)*128 + jcol]    = fmaxf(a3[jl][0][r] + b, 0.f);
                hh[(size_t)(r0+16+g4*4+r)*128 + jcol] = fmaxf(a3[jl][1][r] + b, 0.f);
            }
        }
    }
}

// ---------------- k_sw2: 16 dsts/block; gather x rows into LDS (same pairwise
// sum order as before), then h2 = relu(x @ W2) via split-bf16 MFMA.
__global__ __launch_bounds__(512) void k_sw2(
    const float* __restrict__ hh, const int* __restrict__ cnt,
    const int2* __restrict__ bucket2,
    const uint4* __restrict__ w2h, const uint4* __restrict__ w2l,
    const float* __restrict__ b2, float* __restrict__ h2)
{
    __shared__ float sx[16][132];
    int tid = threadIdx.x;
    int bidd0 = blockIdx.x * 16;
    {
        int dloc = tid >> 5;          // 0..15
        int j4 = tid & 31;            // float4 column group
        int cell = bidd0 + dloc;
        int t = cell >> 9;
        int n = cnt[cell]; n = n < CAP ? n : CAP;
        const int2* __restrict__ bk = &bucket2[(size_t)cell*CAP];
        const float* __restrict__ hht = &hh[(size_t)t*Nn*128];
        float4 acc = *(const float4*)&hh[(size_t)cell*128 + j4*4];
        int i = 0;
        for (; i+1 < n; i += 2){
            int2 p0 = bk[i], p1 = bk[i+1];
            float w0 = __int_as_float(p0.y), w1 = __int_as_float(p1.y);
            float4 r0 = *(const float4*)&hht[(size_t)p0.x*128 + j4*4];
            float4 r1 = *(const float4*)&hht[(size_t)p1.x*128 + j4*4];
            acc.x += w0*r0.x + w1*r1.x;
            acc.y += w0*r0.y + w1*r1.y;
            acc.z += w0*r0.z + w1*r1.z;
            acc.w += w0*r0.w + w1*r1.w;
        }
        if (i < n){
            int2 p = bk[i];
            float w = __int_as_float(p.y);
            float4 r = *(const float4*)&hht[(size_t)p.x*128 + j4*4];
            acc.x += w*r.x; acc.y += w*r.y; acc.z += w*r.z; acc.w += w*r.w;
        }
        *(float4*)&sx[dloc][j4*4] = acc;
    }
    __syncthreads();
    // MFMA: h2[16 x 128] = relu(sx @ W2 + b2); wave w owns jt = w (8 waves)
    int w = tid >> 6, lane = tid & 63;
    int r16 = lane & 15, g4 = lane >> 4;
    f32x4 a = (f32x4){0.f,0.f,0.f,0.f};
#pragma unroll
    for (int kt=0;kt<4;++kt){
        int k0 = kt*32 + g4*8;
        BU Ah, Al;
        { float4 xa = *(const float4*)&sx[r16][k0]; float4 ya = *(const float4*)&sx[r16][k0+4]; DECA(Ah,Al,xa,ya) }
        BU Bh, Bl;
        Bh.q = w2h[(kt*8+w)*64 + lane];
        Bl.q = w2l[(kt*8+w)*64 + lane];
        a = __builtin_amdgcn_mfma_f32_16x16x32_bf16(Ah.v, Bh.v, a, 0,0,0);
        a = __builtin_amdgcn_mfma_f32_16x16x32_bf16(Ah.v, Bl.v, a, 0,0,0);
        a = __builtin_amdgcn_mfma_f32_16x16x32_bf16(Al.v, Bh.v, a, 0,0,0);
    }
    int jcol = w*16 + r16;
    float b = b2[jcol];
#pragma unroll
    for (int r=0;r<4;++r)
        h2[(size_t)(bidd0 + g4*4 + r)*128 + jcol] = fmaxf(a[r] + b, 0.f);
}

// ---------------- edge scores via split-bf16 MFMA, fragment-pipelined (R18/R20 version)
__global__ __launch_bounds__(512) void k_edge9(
    const int* __restrict__ ei, const float* __restrict__ h2,
    const uint4* __restrict__ w3h, const uint4* __restrict__ w3l,
    const float* __restrict__ b3, const float* __restrict__ w4,
    const float* __restrict__ b4, float* __restrict__ sc)
{
    __shared__ uint4 sBh[2048];   // 32 KB
    __shared__ uint4 sBl[2048];   // 32 KB
    int tid = threadIdx.x;
    int bid = blockIdx.x;                  // < 512
#pragma unroll
    for (int q=0;q<4;++q){
        sBh[q*512+tid] = w3h[q*512+tid];
        sBl[q*512+tid] = w3l[q*512+tid];
    }
    int tb  = bid >> 6;                    // timestep (64 blocks/t)
    int e0b = (bid & 63) * 256;
    int w   = tid >> 6, lane = tid & 63;
    int e0w = e0b + w*32;
    int r16 = lane & 15, g4 = lane >> 4;

    const int* __restrict__ eit = &ei[tb*2*Ee];
    int a0 = eit[e0w + r16],      s0 = eit[Ee + e0w + r16];
    int a1 = eit[e0w + 16 + r16], s1 = eit[Ee + e0w + 16 + r16];
    const float* __restrict__ pa0 = &h2[(size_t)(tb*Nn+a0)*128];
    const float* __restrict__ pb0 = &h2[(size_t)(tb*Nn+s0)*128];
    const float* __restrict__ pa1 = &h2[(size_t)(tb*Nn+a1)*128];
    const float* __restrict__ pb1 = &h2[(size_t)(tb*Nn+s1)*128];

    f32x4 acc0[8], acc1[8];
#pragma unroll
    for (int jt=0;jt<8;++jt){
        acc0[jt] = (f32x4){0.f,0.f,0.f,0.f};
        acc1[jt] = (f32x4){0.f,0.f,0.f,0.f};
    }

    float4 rA0,rA1,rB0,rB1,rC0,rC1,rD0,rD1;
#define LOADK(kt) { int k0=(kt)*32+g4*8; \
    rA0=*(const float4*)&pa0[k0]; rA1=*(const float4*)&pa0[k0+4]; \
    rB0=*(const float4*)&pb0[k0]; rB1=*(const float4*)&pb0[k0+4]; \
    rC0=*(const float4*)&pa1[k0]; rC1=*(const float4*)&pa1[k0+4]; \
    rD0=*(const float4*)&pb1[k0]; rD1=*(const float4*)&pb1[k0+4]; }

    BU ah0[2], al0[2], ah1[2], al1[2];
#define DECK(s) { uint4 hq,lq; \
    dec2(rA0.x*rB0.x, rA0.y*rB0.y, hq.x, lq.x); \
    dec2(rA0.z*rB0.z, rA0.w*rB0.w, hq.y, lq.y); \
    dec2(rA1.x*rB1.x, rA1.y*rB1.y, hq.z, lq.z); \
    dec2(rA1.z*rB1.z, rA1.w*rB1.w, hq.w, lq.w); \
    ah0[s].q=hq; al0[s].q=lq; \
    dec2(rC0.x*rD0.x, rC0.y*rD0.y, hq.x, lq.x); \
    dec2(rC0.z*rD0.z, rC0.w*rD0.w, hq.y, lq.y); \
    dec2(rC1.x*rD1.x, rC1.y*rD1.y, hq.z, lq.z); \
    dec2(rC1.z*rD1.z, rC1.w*rD1.w, hq.w, lq.w); \
    ah1[s].q=hq; al1[s].q=lq; }

    LOADK(0)
    DECK(0)
    __syncthreads();
#pragma unroll
    for (int kt=0;kt<4;++kt){
        if (kt < 3) LOADK(kt+1)
        const int s = kt & 1;
#pragma unroll
        for (int jt=0;jt<8;++jt){
            BU Bh, Bl;
            Bh.q = sBh[(kt*8+jt)*64 + lane];
            Bl.q = sBl[(kt*8+jt)*64 + lane];
            acc0[jt] = __builtin_amdgcn_mfma_f32_16x16x32_bf16(ah0[s].v, Bh.v, acc0[jt], 0,0,0);
            acc0[jt] = __builtin_amdgcn_mfma_f32_16x16x32_bf16(ah0[s].v, Bl.v, acc0[jt], 0,0,0);
            acc0[jt] = __builtin_amdgcn_mfma_f32_16x16x32_bf16(al0[s].v, Bh.v, acc0[jt], 0,0,0);
            acc1[jt] = __builtin_amdgcn_mfma_f32_16x16x32_bf16(ah1[s].v, Bh.v, acc1[jt], 0,0,0);
            acc1[jt] = __builtin_amdgcn_mfma_f32_16x16x32_bf16(ah1[s].v, Bl.v, acc1[jt], 0,0,0);
            acc1[jt] = __builtin_amdgcn_mfma_f32_16x16x32_bf16(al1[s].v, Bh.v, acc1[jt], 0,0,0);
        }
        if (kt < 3) DECK((kt+1)&1)
    }

    float b4v = b4[0];
    float b3v[8], w4v[8];
#pragma unroll
    for (int jt=0;jt<8;++jt){ b3v[jt] = b3[jt*16 + r16]; w4v[jt] = w4[jt*16 + r16]; }
#pragma unroll
    for (int r=0;r<4;++r){
        float p0 = 0.f, p1 = 0.f;
#pragma unroll
        for (int jt=0;jt<8;++jt){
            p0 += fmaxf(acc0[jt][r] + b3v[jt], 0.f) * w4v[jt];
            p1 += fmaxf(acc1[jt][r] + b3v[jt], 0.f) * w4v[jt];
        }
        p0 += __shfl_xor(p0,1); p0 += __shfl_xor(p0,2);
        p0 += __shfl_xor(p0,4); p0 += __shfl_xor(p0,8);
        p1 += __shfl_xor(p1,1); p1 += __shfl_xor(p1,2);
        p1 += __shfl_xor(p1,4); p1 += __shfl_xor(p1,8);
        if (r16 == 0){
            sc[(size_t)tb*Ee + e0w + g4*4 + r]      = p0 + b4v;
            sc[(size_t)tb*Ee + e0w + 16 + g4*4 + r] = p1 + b4v;
        }
    }
}

// ---------------- SSM recurrence (reads tag+sc directly)
__global__ __launch_bounds__(256) void k_ssm2(
    const int* __restrict__ ei, const int* __restrict__ tag,
    const float* __restrict__ sc,
    const float* __restrict__ W_in, const float* __restrict__ conv_w,
    const float* __restrict__ conv_b, const float* __restrict__ dt_bias,
    const float* __restrict__ A_log, const float* __restrict__ D_skip,
    const float* __restrict__ W_out, float* __restrict__ out)
{
    __shared__ float scw[132], scb[33], swin[35];
    int tid = threadIdx.x;
    if (tid < 132) scw[tid] = conv_w[tid];
    if (tid < 33)  scb[tid] = conv_b[tid];
    if (tid < 35)  swin[tid] = W_in[tid];
    __syncthreads();

    int e = blockIdx.x*256 + tid;              // < E
    int a = ei[7*2*Ee + e], b = ei[7*2*Ee + Ee + e];
    int cell = a*Nn + b;
    float x[8];
#pragma unroll
    for (int t=0;t<8;++t){
        int tg = tag[t*NNc + cell];
        x[t] = (tg > 0) ? sc[tg-1] : 0.f;
    }

    float A    = -expf(A_log[0]);
    float dtb  = dt_bias[0];
    float dsk  = D_skip[0];
    float wout = W_out[0];
    float win_z = swin[0], win_dt = swin[34];

    float ssm[16];
#pragma unroll
    for (int q=0;q<16;++q) ssm[q]=0.f;
    float h0=0.f,h1=0.f,h2v=0.f;
    float y=0.f;
    for (int t=0;t<8;++t){
        float xt = x[t];
        float act[33];
#pragma unroll
        for (int c=0;c<33;++c){
            float s = h0*scw[c*4+0] + h1*scw[c*4+1] + h2v*scw[c*4+2] + xt*scw[c*4+3];
            float pre = swin[1+c]*s + scb[c];
            act[c] = pre / (1.f + expf(-pre));
        }
        float x_ = act[0];
        float dtr = xt*win_dt + dtb;
        float dt  = (dtr > 20.f) ? dtr : log1pf(expf(dtr));
        float dA  = expf(dt*A);
        float dx  = dt*x_;
        float yv = 0.f;
#pragma unroll
        for (int q=0;q<16;++q){
            ssm[q] = ssm[q]*dA + dx*act[1+q];
            yv += ssm[q]*act[17+q];
        }
        yv += dsk*x_;
        float z = xt*win_z;
        yv *= z / (1.f + expf(-z));
        y = yv;
        h0=h1; h1=h2v; h2v=xt;
    }
    out[cell] = y*wout;
}

extern "C" void kernel_launch(void* const* d_in, const int* in_sizes, int n_in,
                              void* d_out, int out_size, void* d_ws, size_t ws_size,
                              hipStream_t stream)
{
    const int*   ei    = (const int*)d_in[0];
    const float* ew    = (const float*)d_in[1];
    const float* feats = (const float*)d_in[2];
    const float* noise = (const float*)d_in[3];
    const float* Wp1=(const float*)d_in[4];  const float* bp1=(const float*)d_in[5];
    const float* Wp2=(const float*)d_in[6];  const float* bp2=(const float*)d_in[7];
    const float* W1 =(const float*)d_in[8];  const float* b1 =(const float*)d_in[9];
    const float* W2 =(const float*)d_in[10]; const float* b2 =(const float*)d_in[11];
    const float* W3 =(const float*)d_in[12]; const float* b3 =(const float*)d_in[13];
    const float* w4 =(const float*)d_in[14]; const float* b4 =(const float*)d_in[15];
    const float* W_in  =(const float*)d_in[16]; const float* conv_w=(const float*)d_in[17];
    const float* conv_b=(const float*)d_in[18]; const float* dt_bias=(const float*)d_in[19];
    const float* A_log =(const float*)d_in[20]; const float* D_skip=(const float*)d_in[21];
    const float* W_out =(const float*)d_in[22];

    float* out = (float*)d_out;
    float* ws  = (float*)d_ws;
    float* hh    = ws;                      // T*N*128  = 524288
    float* h2    = hh    + 524288;          // 524288
    float* sc    = h2    + 524288;          // T*E      = 131072
    int*   cnt   = (int*)(sc + 131072);     // T*N      = 4096
    int*   tag   = cnt + TNr;               // T*N*N    = 2097152
    int2*  bucket2 = (int2*)(tag + 2097152);           // T*N*CAP int2 = 4MB
    unsigned short* w3h = (unsigned short*)(bucket2 + (size_t)TNr*CAP);  // 16384
    unsigned short* w3l = w3h + 16384;      // 16384
    unsigned short* p1h = w3l + 16384;      // 32768
    unsigned short* p1l = p1h + 32768;      // 32768
    unsigned short* p2h = p1l + 32768;      // 16384
    unsigned short* p2l = p2h + 16384;      // 16384
    unsigned short* p3h = p2l + 16384;      // 12288
    unsigned short* p3l = p3h + 12288;      // 12288
    unsigned short* w2h = p3l + 12288;      // 16384
    unsigned short* w2l = w2h + 16384;      // 16384

    k_prep <<<368, 256, 0, stream>>>(ei, W3, Wp1, Wp2, W1, W2,
                                     w3h, w3l, p1h, p1l, p2h, p2l, p3h, p3l,
                                     w2h, w2l, cnt, tag, (float4*)out);
    k_mid  <<<640, 256, 0, stream>>>(ei, ew, cnt, bucket2, tag, feats, noise,
                                     (const uint4*)p1h, (const uint4*)p1l, bp1,
                                     (const uint4*)p2h, (const uint4*)p2l, bp2,
                                     (const uint4*)p3h, (const uint4*)p3l, b1, hh);
    k_sw2  <<<TNr/16, 512, 0, stream>>>(hh, cnt, bucket2,
                                        (const uint4*)w2h, (const uint4*)w2l, b2, h2);
    k_edge9<<<512, 512, 0, stream>>>(ei, h2, (const uint4*)w3h, (const uint4*)w3l,
                                     b3, w4, b4, sc);
    k_ssm2 <<<Ee/256, 256, 0, stream>>>(ei, tag, sc, W_in, conv_w, conv_b,
                                        dt_bias, A_log, D_skip, W_out, out);
}